// Round 1
// baseline (44.056 us; speedup 1.0000x reference)
//
#include <hip/hip_runtime.h>
#include <math.h>

#define MODES 32
#define WAVE  64
#define CHUNK 1024
#define INV2PI 0.15915494309189535f

// sin/cos of (2*pi*rev): v_sin_f32 / v_cos_f32 take REVOLUTIONS; reduce to [0,1) first.
__device__ inline void sincos_rev(float rev, float& s, float& c) {
    float f = rev - floorf(rev);
    s = __builtin_amdgcn_sinf(f);
    c = __builtin_amdgcn_cosf(f);
}

__global__ __launch_bounds__(256) void ssm_vand_kernel(
    const float* __restrict__ C_real,      // (H, MODES, 2)
    const float* __restrict__ log_dt,      // (H,)
    const float* __restrict__ log_A_real,  // (H, MODES)
    const float* __restrict__ A_imag,      // (H, MODES)
    float* __restrict__ K,                 // (H, L)
    int H, int L, int nchunks)
{
    const int gtid = blockIdx.x * blockDim.x + threadIdx.x;
    const int wave = gtid / WAVE;
    const int lane = threadIdx.x & (WAVE - 1);
    const int h = wave / nchunks;
    const int chunk = wave - h * nchunks;
    if (h >= H) return;
    const int l0 = chunk * CHUNK;

    const float dt = __expf(log_dt[h]);
    const float tl = (float)(l0 + lane);   // this lane's starting l (integer, exact in f32)

    float sre[MODES], sim[MODES], wre[MODES], wim[MODES];

#pragma unroll
    for (int n = 0; n < MODES; ++n) {
        const int idx = h * MODES + n;
        const float Ar = -__expf(log_A_real[idx]);
        const float Ai = A_imag[idx];
        const float dAr = dt * Ar;                 // Re(dt*A)
        const float dAi_rev = dt * Ai * INV2PI;    // Im(dt*A) in revolutions

        // em1 = exp(dtA) - 1
        float sn, cs;
        sincos_rev(dAi_rev, sn, cs);
        const float er   = __expf(dAr);
        const float em1r = er * cs - 1.0f;
        const float em1i = er * sn;

        // Ct = C * em1 / A   (1/A = conj(A)/|A|^2)
        const float inv = 1.0f / (Ar * Ar + Ai * Ai);
        const float fr  = (em1r * Ar + em1i * Ai) * inv;
        const float fi  = (em1i * Ar - em1r * Ai) * inv;
        const float Cr  = C_real[idx * 2 + 0];
        const float Ci  = C_real[idx * 2 + 1];
        const float Ctr = Cr * fr - Ci * fi;
        const float Cti = Cr * fi + Ci * fr;

        // z = exp(dtA * tl). Phase in revolutions via exact split product:
        // rhi has a 12-bit mantissa, tl < 2^12 -> rhi*tl exact; frac() drops whole turns exactly.
        const float rhi  = __uint_as_float(__float_as_uint(dAi_rev) & 0xFFFFF000u);
        const float rlo  = dAi_rev - rhi;          // exact (Sterbenz)
        const float p    = rhi * tl;               // exact
        const float frev = (p - floorf(p)) + rlo * tl;
        float zs, zc;
        sincos_rev(frev, zs, zc);
        const float mag = __expf(dAr * tl);
        sre[n] = (Ctr * zc - Cti * zs) * mag;      // state = Ct * exp(dtA*l)
        sim[n] = (Ctr * zs + Cti * zc) * mag;

        // per-iteration multiplier w64 = exp(dtA * 64); *64 is exact in f32
        const float m64 = __expf(dAr * 64.0f);
        float ws, wc;
        sincos_rev(dAi_rev * 64.0f, ws, wc);
        wre[n] = m64 * wc;
        wim[n] = m64 * ws;
    }

    const int rem  = L - l0;
    const int lmax = rem < CHUNK ? rem : CHUNK;
    const int iters = (lmax + WAVE - 1) / WAVE;
    float* __restrict__ out = K + (size_t)h * L + l0 + lane;

    for (int i = 0; i < iters; ++i) {
        float a0 = 0.f, a1 = 0.f, a2 = 0.f, a3 = 0.f;
#pragma unroll
        for (int n = 0; n < MODES; n += 4) {
            a0 += sre[n + 0];
            a1 += sre[n + 1];
            a2 += sre[n + 2];
            a3 += sre[n + 3];
#pragma unroll
            for (int j = 0; j < 4; ++j) {
                const int m = n + j;
                const float nre = sre[m] * wre[m] - sim[m] * wim[m];
                const float nim = sre[m] * wim[m] + sim[m] * wre[m];
                sre[m] = nre;
                sim[m] = nim;
            }
        }
        if (i * WAVE + lane < lmax)
            out[i * WAVE] = 2.0f * ((a0 + a1) + (a2 + a3));
    }
}

extern "C" void kernel_launch(void* const* d_in, const int* in_sizes, int n_in,
                              void* d_out, int out_size, void* d_ws, size_t ws_size,
                              hipStream_t stream) {
    const float* C_real     = (const float*)d_in[0];
    const float* log_dt     = (const float*)d_in[1];
    const float* log_A_real = (const float*)d_in[2];
    const float* A_imag     = (const float*)d_in[3];
    float* K = (float*)d_out;

    const int H = in_sizes[1];            // log_dt has H elements
    const int L = out_size / H;           // K is (H, L)
    const int nchunks = (L + CHUNK - 1) / CHUNK;

    const int waves   = H * nchunks;
    const int threads = 256;
    const int blocks  = (waves * WAVE + threads - 1) / threads;

    ssm_vand_kernel<<<blocks, threads, 0, stream>>>(
        C_real, log_dt, log_A_real, A_imag, K, H, L, nchunks);
}

// Round 2
// 30.614 us; speedup vs baseline: 1.4391x; 1.4391x over previous
//
#include <hip/hip_runtime.h>
#include <math.h>

#define MODES 32
#define WAVES 4
#define MPW   (MODES / WAVES)   // 8 modes per wave
#define WAVE  64
#define LMAX  4096
#define INV2PI 0.15915494309189535f

typedef float f32x2 __attribute__((ext_vector_type(2)));

// D = A + B (packed)
__device__ inline f32x2 pk_add(f32x2 a, f32x2 b) {
    f32x2 d;
    asm("v_pk_add_f32 %0, %1, %2" : "=v"(d) : "v"(a), "v"(b));
    return d;
}
// D = (a.lo*b.lo, a.lo*b.hi)  -- broadcast a.lo
__device__ inline f32x2 pk_mul_blo(f32x2 a, f32x2 b) {
    f32x2 d;
    asm("v_pk_mul_f32 %0, %1, %2 op_sel:[0,0] op_sel_hi:[0,1]" : "=v"(d) : "v"(a), "v"(b));
    return d;
}
// D = (a.hi*b.lo + c.lo, a.hi*b.hi + c.hi)  -- broadcast a.hi
__device__ inline f32x2 pk_fma_bhi(f32x2 a, f32x2 b, f32x2 c) {
    f32x2 d;
    asm("v_pk_fma_f32 %0, %1, %2, %3 op_sel:[1,0,0] op_sel_hi:[1,1,1]"
        : "=v"(d) : "v"(a), "v"(b), "v"(c));
    return d;
}

// sin/cos of (2*pi*rev): v_sin/v_cos take REVOLUTIONS; reduce to [0,1) first.
__device__ inline void sincos_rev(float rev, float& s, float& c) {
    float f = rev - floorf(rev);
    s = __builtin_amdgcn_sinf(f);
    c = __builtin_amdgcn_cosf(f);
}

__global__ __launch_bounds__(256) void ssm_vand_kernel(
    const float* __restrict__ C_real,      // (H, MODES, 2)
    const float* __restrict__ log_dt,      // (H,)
    const float* __restrict__ log_A_real,  // (H, MODES)
    const float* __restrict__ A_imag,      // (H, MODES)
    float* __restrict__ K,                 // (H, L)
    int L)
{
    __shared__ __align__(16) float lds[WAVES * LMAX];   // 64 KiB

    const int h    = blockIdx.x;
    const int w    = threadIdx.x >> 6;
    const int lane = threadIdx.x & (WAVE - 1);

    const float dt = __expf(log_dt[h]);
    const float tl = (float)lane;            // starting l of this lane (exact in f32)

    f32x2 s[MPW], wa[MPW], wb[MPW];

#pragma unroll
    for (int j = 0; j < MPW; ++j) {
        const int idx = h * MODES + w * MPW + j;
        const float Ar = -__expf(log_A_real[idx]);
        const float Ai = A_imag[idx];
        const float dAr = dt * Ar;                 // Re(dt*A)
        const float dAi_rev = dt * Ai * INV2PI;    // Im(dt*A) in revolutions

        // em1 = exp(dtA) - 1
        float sn, cs;
        sincos_rev(dAi_rev, sn, cs);
        const float er   = __expf(dAr);
        const float em1r = er * cs - 1.0f;
        const float em1i = er * sn;

        // Ct = C * em1 / A   (1/A = conj(A)/|A|^2)
        const float inv = 1.0f / (Ar * Ar + Ai * Ai);
        const float fr  = (em1r * Ar + em1i * Ai) * inv;
        const float fi  = (em1i * Ar - em1r * Ai) * inv;
        const float Cr  = C_real[idx * 2 + 0];
        const float Ci  = C_real[idx * 2 + 1];
        const float Ctr = Cr * fr - Ci * fi;
        const float Cti = Cr * fi + Ci * fr;

        // z = exp(dtA * lane). Phase in revolutions via exact split product
        // (rhi has a 12-bit mantissa; lane < 2^6 -> rhi*lane exact).
        const float rhi  = __uint_as_float(__float_as_uint(dAi_rev) & 0xFFFFF000u);
        const float rlo  = dAi_rev - rhi;          // exact (Sterbenz)
        const float p    = rhi * tl;               // exact
        const float frev = (p - floorf(p)) + rlo * tl;
        float zs, zc;
        sincos_rev(frev, zs, zc);
        const float mag = __expf(dAr * tl);
        s[j].x = (Ctr * zc - Cti * zs) * mag;      // state = Ct * exp(dtA*l)
        s[j].y = (Ctr * zs + Cti * zc) * mag;

        // per-iteration multiplier w64 = exp(dtA * 64)
        const float m64 = __expf(dAr * 64.0f);
        float ws64, wc64;
        sincos_rev(dAi_rev * 64.0f, ws64, wc64);
        wa[j].x = m64 * wc64;  wa[j].y = m64 * ws64;   // ( wc,  ws)
        wb[j].x = -m64 * ws64; wb[j].y = m64 * wc64;   // (-ws,  wc)
    }

    // main loop: lane covers l = lane + 64*i; partial (8 modes) -> LDS
    float* __restrict__ lw = lds + w * LMAX;
    const int iters = (L + WAVE - 1) / WAVE;

#pragma unroll 4
    for (int i = 0; i < iters; ++i) {
        const int l = i * WAVE + lane;
        f32x2 a01 = pk_add(s[0], s[1]);
        f32x2 a23 = pk_add(s[2], s[3]);
        f32x2 a45 = pk_add(s[4], s[5]);
        f32x2 a67 = pk_add(s[6], s[7]);
        a01 = pk_add(a01, a23);
        a45 = pk_add(a45, a67);
        a01 = pk_add(a01, a45);           // (.x = sum of re parts, .y = junk)
        if (l < L) lw[l] = a01.x;
#pragma unroll
        for (int j = 0; j < MPW; ++j) {
            f32x2 t = pk_mul_blo(s[j], wa[j]);   // (re*wc, re*ws)
            s[j] = pk_fma_bhi(s[j], wb[j], t);   // (re*wc - im*ws, re*ws + im*wc)
        }
    }

    __syncthreads();

    // cross-wave reduce: 4 partials per l, float4-vectorized, coalesced store
    const int t = threadIdx.x;
    const float4* __restrict__ l4 = (const float4*)lds;
    float4* __restrict__ out4 = (float4*)(K + (size_t)h * L);
    const int n4 = L >> 2;
    const int row4 = LMAX >> 2;
    for (int idx = t; idx < n4; idx += 256) {
        const float4 v0 = l4[0 * row4 + idx];
        const float4 v1 = l4[1 * row4 + idx];
        const float4 v2 = l4[2 * row4 + idx];
        const float4 v3 = l4[3 * row4 + idx];
        float4 r;
        r.x = 2.0f * ((v0.x + v1.x) + (v2.x + v3.x));
        r.y = 2.0f * ((v0.y + v1.y) + (v2.y + v3.y));
        r.z = 2.0f * ((v0.z + v1.z) + (v2.z + v3.z));
        r.w = 2.0f * ((v0.w + v1.w) + (v2.w + v3.w));
        out4[idx] = r;
    }
}

extern "C" void kernel_launch(void* const* d_in, const int* in_sizes, int n_in,
                              void* d_out, int out_size, void* d_ws, size_t ws_size,
                              hipStream_t stream) {
    const float* C_real     = (const float*)d_in[0];
    const float* log_dt     = (const float*)d_in[1];
    const float* log_A_real = (const float*)d_in[2];
    const float* A_imag     = (const float*)d_in[3];
    float* K = (float*)d_out;

    const int H = in_sizes[1];            // log_dt has H elements
    const int L = out_size / H;           // K is (H, L), L <= LMAX

    ssm_vand_kernel<<<H, 256, 0, stream>>>(
        C_real, log_dt, log_A_real, A_imag, K, L);
}

// Round 3
// 24.289 us; speedup vs baseline: 1.8139x; 1.2604x over previous
//
#include <hip/hip_runtime.h>
#include <math.h>

#define MODES 32
#define WAVES 4
#define MPW   (MODES / WAVES)   // 8 modes per wave
#define WAVE  64
#define INV2PI 0.15915494309189535f

typedef float f32x2 __attribute__((ext_vector_type(2)));

__device__ inline f32x2 pk_add(f32x2 a, f32x2 b) {
    f32x2 d;
    asm("v_pk_add_f32 %0, %1, %2" : "=v"(d) : "v"(a), "v"(b));
    return d;
}
__device__ inline f32x2 pk_mul(f32x2 a, f32x2 b) {
    f32x2 d;
    asm("v_pk_mul_f32 %0, %1, %2" : "=v"(d) : "v"(a), "v"(b));
    return d;
}
__device__ inline f32x2 pk_fma(f32x2 a, f32x2 b, f32x2 c) {
    f32x2 d;
    asm("v_pk_fma_f32 %0, %1, %2, %3" : "=v"(d) : "v"(a), "v"(b), "v"(c));
    return d;
}

// sin/cos of (2*pi*rev): v_sin/v_cos take REVOLUTIONS; reduce to [0,1) first.
__device__ inline void sincos_rev(float rev, float& s, float& c) {
    float f = rev - floorf(rev);
    s = __builtin_amdgcn_sinf(f);
    c = __builtin_amdgcn_cosf(f);
}

__global__ __launch_bounds__(256, 4) void ssm_vand_kernel(
    const float* __restrict__ C_real,      // (H, MODES, 2)
    const float* __restrict__ log_dt,      // (H,)
    const float* __restrict__ log_A_real,  // (H, MODES)
    const float* __restrict__ A_imag,      // (H, MODES)
    float* __restrict__ K,                 // (H, L)
    int L)
{
    // per-wave partial sums: 1024 f32x2 entries per wave (pair = l, l+L/2)
    __shared__ __align__(16) f32x2 lds[WAVES * 1024];   // 32 KiB

    const int h    = blockIdx.x;
    const int w    = threadIdx.x >> 6;
    const int lane = threadIdx.x & (WAVE - 1);

    const float dt    = __expf(log_dt[h]);
    const float tl    = (float)lane;
    const int   HALF  = L >> 1;
    const float halff = (float)HALF;        // 2048: power of two -> exact products

    // state: sr = (re_l, re_{l+HALF}), si = (im_l, im_{l+HALF}) per mode
    // multipliers (lane-uniform, broadcast in both halves): mr=(wr,wr), mi=(wi,wi), mn=(-wi,-wi)
    f32x2 sr[MPW], si[MPW], mr[MPW], mi[MPW], mn[MPW];

#pragma unroll
    for (int j = 0; j < MPW; ++j) {
        const int idx = h * MODES + w * MPW + j;
        const float Ar = -__expf(log_A_real[idx]);
        const float Ai = A_imag[idx];
        const float dAr = dt * Ar;                 // Re(dt*A)
        const float dAi_rev = dt * Ai * INV2PI;    // Im(dt*A) in revolutions

        // em1 = exp(dtA) - 1
        float sn, cs;
        sincos_rev(dAi_rev, sn, cs);
        const float er   = __expf(dAr);
        const float em1r = er * cs - 1.0f;
        const float em1i = er * sn;

        // Ct = C * em1 / A   (1/A = conj(A)/|A|^2)
        const float inv = 1.0f / (Ar * Ar + Ai * Ai);
        const float fr  = (em1r * Ar + em1i * Ai) * inv;
        const float fi  = (em1i * Ar - em1r * Ai) * inv;
        const float Cr  = C_real[idx * 2 + 0];
        const float Ci  = C_real[idx * 2 + 1];
        const float Ctr = Cr * fr - Ci * fi;
        const float Cti = Cr * fi + Ci * fr;

        // exact split of the phase step (rhi keeps 12 mantissa bits)
        const float rhi = __uint_as_float(__float_as_uint(dAi_rev) & 0xFFFFF000u);
        const float rlo = dAi_rev - rhi;           // exact (Sterbenz)

        // z = exp(dtA * lane); rhi*tl exact (12b x 6b), frac drops turns exactly
        const float p0   = rhi * tl;
        const float fre0 = (p0 - floorf(p0)) + rlo * tl;
        float zs, zc;
        sincos_rev(fre0, zs, zc);
        const float mag = __expf(dAr * tl);
        const float reA = (Ctr * zc - Cti * zs) * mag;   // state at l = lane
        const float imA = (Ctr * zs + Cti * zc) * mag;

        // W = exp(dtA * HALF); HALF = 2^11 so all products are exact shifts
        const float p1  = rhi * halff;
        const float fh  = (p1 - floorf(p1)) + rlo * halff;
        float hs, hc;
        sincos_rev(fh, hs, hc);
        const float hm  = __expf(dAr * halff);
        const float w2r = hm * hc, w2i = hm * hs;
        const float reB = reA * w2r - imA * w2i;         // state at l = lane + HALF
        const float imB = reA * w2i + imA * w2r;

        sr[j].x = reA; sr[j].y = reB;
        si[j].x = imA; si[j].y = imB;

        // per-iteration multiplier w64 = exp(dtA * 64) (same for both halves)
        const float m64 = __expf(dAr * 64.0f);
        float ws, wc;
        sincos_rev(dAi_rev * 64.0f, ws, wc);
        mr[j].x = m64 * wc;  mr[j].y = m64 * wc;
        mi[j].x = m64 * ws;  mi[j].y = m64 * ws;
        mn[j].x = -m64 * ws; mn[j].y = -m64 * ws;
    }

    f32x2* __restrict__ lw = lds + w * 1024;
    float* __restrict__ Kh = K + (size_t)h * L;
    const int nseg = HALF >> 10;               // 1024 low-l's per segment

    for (int seg = 0; seg < nseg; ++seg) {
#pragma unroll
        for (int i = 0; i < 16; ++i) {
            // sum of re-parts over this wave's 8 modes, both l's at once
            f32x2 a01 = pk_add(sr[0], sr[1]);
            f32x2 a23 = pk_add(sr[2], sr[3]);
            f32x2 a45 = pk_add(sr[4], sr[5]);
            f32x2 a67 = pk_add(sr[6], sr[7]);
            a01 = pk_add(a01, a23);
            a45 = pk_add(a45, a67);
            lw[i * WAVE + lane] = pk_add(a01, a45);
            // advance both halves by w64: s *= (wr + i*wi)
#pragma unroll
            for (int jj = 0; jj < MPW; ++jj) {
                f32x2 t0 = pk_mul(sr[jj], mr[jj]);   // re*wr
                f32x2 t1 = pk_mul(sr[jj], mi[jj]);   // re*wi
                sr[jj] = pk_fma(si[jj], mn[jj], t0); // re*wr - im*wi
                si[jj] = pk_fma(si[jj], mr[jj], t1); // re*wi + im*wr
            }
        }
        __syncthreads();

        // cross-wave reduce: 4 partials per pair-entry, coalesced scalar stores
        const int base = seg * 1024;
#pragma unroll
        for (int k = 0; k < 4; ++k) {
            const int p = k * 256 + threadIdx.x;
            f32x2 v = pk_add(pk_add(lds[p], lds[1024 + p]),
                             pk_add(lds[2048 + p], lds[3072 + p]));
            Kh[base + p]        = 2.0f * v.x;
            Kh[base + p + HALF] = 2.0f * v.y;
        }
        __syncthreads();
    }
}

extern "C" void kernel_launch(void* const* d_in, const int* in_sizes, int n_in,
                              void* d_out, int out_size, void* d_ws, size_t ws_size,
                              hipStream_t stream) {
    const float* C_real     = (const float*)d_in[0];
    const float* log_dt     = (const float*)d_in[1];
    const float* log_A_real = (const float*)d_in[2];
    const float* A_imag     = (const float*)d_in[3];
    float* K = (float*)d_out;

    const int H = in_sizes[1];            // log_dt has H elements
    const int L = out_size / H;           // K is (H, L); L = 4096

    ssm_vand_kernel<<<H, 256, 0, stream>>>(
        C_real, log_dt, log_A_real, A_imag, K, L);
}

// Round 4
// 12.807 us; speedup vs baseline: 3.4400x; 1.8965x over previous
//
#include <hip/hip_runtime.h>
#include <math.h>

#define NMODES 32
#define INV2PI 0.15915494309189535f

typedef short bf16x8 __attribute__((ext_vector_type(8)));  // 8 bf16 (4 VGPRs)
typedef float f32x4  __attribute__((ext_vector_type(4)));  // MFMA C/D

// sin/cos of (2*pi*rev): v_sin/v_cos take REVOLUTIONS; reduce to [0,1) first.
__device__ inline void sincos_rev(float rev, float& s, float& c) {
    float f = rev - floorf(rev);
    s = __builtin_amdgcn_sinf(f);
    c = __builtin_amdgcn_cosf(f);
}

// Truncation split: x = hi + lo, hi = bf16-truncate(x) (exact residual lo).
__device__ inline void split_bf(float x, short& hi, short& lo) {
    const unsigned u = __float_as_uint(x);
    const float xf = __uint_as_float(u & 0xFFFF0000u);
    hi = (short)(u >> 16);
    const float r = x - xf;                         // exact
    lo = (short)(__float_as_uint(r) >> 16);
}

// One wave per h. K[h, 64*i + d] = 2 * sum_k A[i,k] B[k,d],
//   A[i, m]    =  Re(Ct[m] * exp(dtA[m]*64i)),  A[i, m+32] = -Im(...)
//   B[m, d]    =  Re(exp(dtA[m]*d)),            B[m+32, d] =  Im(...)
// MFMA 16x16x32 bf16 layouts: A[row=lane&15][k=(lane>>4)*8+j],
// B[k=(lane>>4)*8+j][col=lane&15], D[row=(lane>>4)*4+reg][col=lane&15].
__global__ __launch_bounds__(64) void ssm_mfma_kernel(
    const float* __restrict__ C_real,      // (H, 32, 2)
    const float* __restrict__ log_dt,      // (H,)
    const float* __restrict__ log_A_real,  // (H, 32)
    const float* __restrict__ A_imag,      // (H, 32)
    float* __restrict__ K,                 // (H, 4096)
    int L)
{
    const int h    = blockIdx.x;
    const int lane = threadIdx.x;          // 0..63
    const int r    = lane & 15;
    const int g    = lane >> 4;            // this lane's 8 modes: g*8 .. g*8+7

    const float dt = __expf(log_dt[h]);

    // B fragments: [re/im chunk][hi/lo split][delta-block]
    bf16x8 Bh0[4], Bl0[4], Bh1[4], Bl1[4];
    float dAr_[8], rhi_[8], rlo_[8], Ctr_[8], Cti_[8];

#pragma unroll
    for (int j = 0; j < 8; ++j) {
        const int m   = g * 8 + j;
        const int idx = h * NMODES + m;
        const float Ar = -__expf(log_A_real[idx]);
        const float Ai = A_imag[idx];
        const float dAr = dt * Ar;
        const float dAi_rev = dt * Ai * INV2PI;     // phase step in revolutions

        // exact 12-bit split of the phase step
        const float rhi = __uint_as_float(__float_as_uint(dAi_rev) & 0xFFFFF000u);
        const float rlo = dAi_rev - rhi;            // exact (<=12 sig bits)

        // Ct = C * (exp(dtA)-1) / A
        float sn, cs;
        sincos_rev(dAi_rev, sn, cs);
        const float er   = __expf(dAr);
        const float em1r = er * cs - 1.0f;
        const float em1i = er * sn;
        const float inv  = 1.0f / (Ar * Ar + Ai * Ai);
        const float fr   = (em1r * Ar + em1i * Ai) * inv;
        const float fi   = (em1i * Ar - em1r * Ai) * inv;
        const float Cr   = C_real[idx * 2 + 0];
        const float Ci   = C_real[idx * 2 + 1];
        const float Ctr  = Cr * fr - Ci * fi;
        const float Cti  = Cr * fi + Ci * fr;

        dAr_[j] = dAr; rhi_[j] = rhi; rlo_[j] = rlo; Ctr_[j] = Ctr; Cti_[j] = Cti;

        // B elements: Q[m, d] for d = r + 16*b  (rhi*d exact: 12b x 6b)
#pragma unroll
        for (int b = 0; b < 4; ++b) {
            const float d  = (float)(r + 16 * b);
            const float pm = __expf(dAr * d);
            const float p  = rhi * d;
            const float f  = (p - floorf(p)) + rlo * d;
            float qs, qc;
            sincos_rev(f, qs, qc);
            const float qr = pm * qc;
            const float qi = pm * qs;
            short hh, ll;
            split_bf(qr, hh, ll); Bh0[b][j] = hh; Bl0[b][j] = ll;
            split_bf(qi, hh, ll); Bh1[b][j] = hh; Bl1[b][j] = ll;
        }
    }

    float* __restrict__ Kh = K + (size_t)h * L;

#pragma unroll
    for (int a = 0; a < 4; ++a) {
        // A fragments for i = r + 16*a: G = Ct * exp(dtA * 64i)
        bf16x8 Ah0, Al0, Ah1, Al1;
#pragma unroll
        for (int j = 0; j < 8; ++j) {
            const float t  = (float)(64 * (r + 16 * a));   // <= 4032, 6 sig bits
            const float pm = __expf(dAr_[j] * t);
            const float p  = rhi_[j] * t;                  // exact (12b x 6b)
            const float f  = (p - floorf(p)) + rlo_[j] * t; // rlo*t exact
            float zs, zc;
            sincos_rev(f, zs, zc);
            const float gr  = (Ctr_[j] * zc - Cti_[j] * zs) * pm;
            const float gni = -(Ctr_[j] * zs + Cti_[j] * zc) * pm;
            short hh, ll;
            split_bf(gr, hh, ll);  Ah0[j] = hh; Al0[j] = ll;
            split_bf(gni, hh, ll); Ah1[j] = hh; Al1[j] = ll;
        }

#pragma unroll
        for (int b = 0; b < 4; ++b) {
            f32x4 acc = {0.f, 0.f, 0.f, 0.f};
            // hi*hi + hi*lo + lo*hi (lo*lo dropped, ~2^-18)
            acc = __builtin_amdgcn_mfma_f32_16x16x32_bf16(Ah0, Bh0[b], acc, 0, 0, 0);
            acc = __builtin_amdgcn_mfma_f32_16x16x32_bf16(Ah1, Bh1[b], acc, 0, 0, 0);
            acc = __builtin_amdgcn_mfma_f32_16x16x32_bf16(Ah0, Bl0[b], acc, 0, 0, 0);
            acc = __builtin_amdgcn_mfma_f32_16x16x32_bf16(Ah1, Bl1[b], acc, 0, 0, 0);
            acc = __builtin_amdgcn_mfma_f32_16x16x32_bf16(Al0, Bh0[b], acc, 0, 0, 0);
            acc = __builtin_amdgcn_mfma_f32_16x16x32_bf16(Al1, Bh1[b], acc, 0, 0, 0);
            // D[row = 4g + reg][col = r] -> K[64*(16a + 4g + reg) + 16b + r]
#pragma unroll
            for (int reg = 0; reg < 4; ++reg) {
                Kh[64 * (16 * a + 4 * g + reg) + 16 * b + r] = 2.0f * acc[reg];
            }
        }
    }
}

extern "C" void kernel_launch(void* const* d_in, const int* in_sizes, int n_in,
                              void* d_out, int out_size, void* d_ws, size_t ws_size,
                              hipStream_t stream) {
    const float* C_real     = (const float*)d_in[0];
    const float* log_dt     = (const float*)d_in[1];
    const float* log_A_real = (const float*)d_in[2];
    const float* A_imag     = (const float*)d_in[3];
    float* K = (float*)d_out;

    const int H = in_sizes[1];            // log_dt has H elements
    const int L = out_size / H;           // 4096

    ssm_mfma_kernel<<<H, 64, 0, stream>>>(
        C_real, log_dt, log_A_real, A_imag, K, L);
}